// Round 1
// baseline (555.822 us; speedup 1.0000x reference)
//
#include <hip/hip_runtime.h>

// Problem constants (match reference setup_inputs)
#define B_    32
#define N_    2000
#define E_    64000
#define EMBED 128
#define ACC_STRIDE 5   // [sum_xsrc0, sum_xsrc1, sum_ea0, sum_ea1, cnt]

// ---------------------------------------------------------------------------
// Kernel 1: per-edge scatter of the 5 linear sufficient statistics.
//   accum[b][tgt] += [x_src.x, x_src.y, ea.x, ea.y, 1]
// ---------------------------------------------------------------------------
__global__ void edge_scatter_kernel(const float* __restrict__ locs,
                                    const int*   __restrict__ edge_index,
                                    const float* __restrict__ edge_attr,
                                    float*       __restrict__ accum) {
    int idx = blockIdx.x * blockDim.x + threadIdx.x;
    const int total = B_ * E_;
    if (idx >= total) return;
    int b = idx / E_;
    int e = idx - b * E_;

    const int* ei = edge_index + (size_t)b * 2 * E_;
    int src = ei[e];        // ei[b][0][e]
    int tgt = ei[E_ + e];   // ei[b][1][e]

    const float* xb = locs + (size_t)b * N_ * 2;
    float2 xs = *reinterpret_cast<const float2*>(xb + (size_t)src * 2);
    float2 ea = *reinterpret_cast<const float2*>(edge_attr + ((size_t)b * E_ + e) * 2);

    float* a = accum + ((size_t)b * N_ + tgt) * ACC_STRIDE;
    atomicAdd(a + 0, xs.x);
    atomicAdd(a + 1, xs.y);
    atomicAdd(a + 2, ea.x);
    atomicAdd(a + 3, ea.y);
    atomicAdd(a + 4, 1.0f);
}

// ---------------------------------------------------------------------------
// Kernel 2: dense finalize.
//   out[b][n][k] = (W[k]·[cnt*x, sum_xsrc, sum_ea] + cnt*bias[k]) / max(cnt,1)
// W staged in LDS transposed: sWt[j*EMBED + k] -> lane k reads bank k%32,
// conflict-free across the wave.
// ---------------------------------------------------------------------------
__global__ void finalize_kernel(const float* __restrict__ locs,
                                const float* __restrict__ accum,
                                const float* __restrict__ W,     // [EMBED][6]
                                const float* __restrict__ bias,  // [EMBED]
                                float*       __restrict__ out) { // [B][N][EMBED]
    __shared__ float sWt[6 * EMBED];
    __shared__ float sb[EMBED];
    int k = threadIdx.x;  // 0..127 = embedding channel
    #pragma unroll
    for (int j = 0; j < 6; ++j) sWt[j * EMBED + k] = W[k * 6 + j];
    sb[k] = bias[k];
    __syncthreads();

    float w0 = sWt[0 * EMBED + k];
    float w1 = sWt[1 * EMBED + k];
    float w2 = sWt[2 * EMBED + k];
    float w3 = sWt[3 * EMBED + k];
    float w4 = sWt[4 * EMBED + k];
    float w5 = sWt[5 * EMBED + k];
    float bk = sb[k];

    for (int bn = blockIdx.x; bn < B_ * N_; bn += gridDim.x) {
        const float* a = accum + (size_t)bn * ACC_STRIDE;
        float s0 = a[0], s1 = a[1], s2 = a[2], s3 = a[3], cnt = a[4];
        float2 x = *reinterpret_cast<const float2*>(locs + (size_t)bn * 2);
        float f0 = cnt * x.x;
        float f1 = cnt * x.y;
        float v = w0 * f0 + w1 * f1 + w2 * s0 + w3 * s1 + w4 * s2 + w5 * s3 + cnt * bk;
        out[(size_t)bn * EMBED + k] = v / fmaxf(cnt, 1.0f);
    }
}

extern "C" void kernel_launch(void* const* d_in, const int* in_sizes, int n_in,
                              void* d_out, int out_size, void* d_ws, size_t ws_size,
                              hipStream_t stream) {
    const float* locs       = (const float*)d_in[0];  // [B][N][2]
    const int*   edge_index = (const int*)  d_in[1];  // [B][2][E]
    const float* edge_attr  = (const float*)d_in[2];  // [B][E][2]
    const float* W          = (const float*)d_in[3];  // [128][6]
    const float* bias       = (const float*)d_in[4];  // [128]
    float* out = (float*)d_out;                       // [B][N][128]

    float* accum = (float*)d_ws;                      // [B][N][5]
    const size_t accum_bytes = (size_t)B_ * N_ * ACC_STRIDE * sizeof(float);

    hipMemsetAsync(accum, 0, accum_bytes, stream);

    // Edge scatter: one thread per edge.
    {
        const int total = B_ * E_;            // 2,048,000
        const int block = 256;
        const int grid  = (total + block - 1) / block;
        edge_scatter_kernel<<<grid, block, 0, stream>>>(locs, edge_index, edge_attr, accum);
    }

    // Finalize: grid-stride over (b,n), 128 threads = 128 channels.
    {
        const int block = 128;
        const int grid  = 2048;
        finalize_kernel<<<grid, block, 0, stream>>>(locs, accum, W, bias, out);
    }
}

// Round 2
// 217.063 us; speedup vs baseline: 2.5607x; 2.5607x over previous
//
#include <hip/hip_runtime.h>

// Problem constants (match reference setup_inputs)
#define B_    32
#define N_    2000
#define E_    64000
#define EMBED 128
#define STATS 5   // [sum_xsrc0, sum_xsrc1, sum_ea0, sum_ea1, cnt]

// ---------------------------------------------------------------------------
// Kernel 1: per-edge scatter into a per-block LDS accumulator (40 KB), then
// one coalesced flush of the partial to global ws. No global atomics.
// Grid = B_ * BPS blocks; block (b, blk) handles edges [blk*epb, (blk+1)*epb).
// LDS addressing: node n stat s -> word (5n+s); stride 5 is odd so consecutive
// stats/nodes cycle through all 32 banks; random targets => ~2 lanes/bank.
// ---------------------------------------------------------------------------
__global__ __launch_bounds__(256) void edge_scatter_lds(
        const float* __restrict__ locs,
        const int*   __restrict__ edge_index,
        const float* __restrict__ edge_attr,
        float*       __restrict__ partials,   // [B][BPS][N][STATS]
        int bps, int epb) {
    __shared__ float acc[N_ * STATS];  // 40 KB

    const int b   = blockIdx.x / bps;
    const int blk = blockIdx.x - b * bps;

    for (int i = threadIdx.x; i < N_ * STATS; i += blockDim.x) acc[i] = 0.0f;
    __syncthreads();

    const int*   eib = edge_index + (size_t)b * 2 * E_;
    const float* eab = edge_attr  + (size_t)b * E_ * 2;
    const float* xb  = locs       + (size_t)b * N_ * 2;

    const int e0 = blk * epb;
    const int e1 = e0 + epb;
    for (int e = e0 + threadIdx.x; e < e1; e += blockDim.x) {
        int src = eib[e];        // ei[b][0][e]
        int tgt = eib[E_ + e];   // ei[b][1][e]
        float2 xs = *reinterpret_cast<const float2*>(xb + (size_t)src * 2);
        float2 ea = *reinterpret_cast<const float2*>(eab + (size_t)e * 2);
        float* a = acc + tgt * STATS;
        atomicAdd(a + 0, xs.x);
        atomicAdd(a + 1, xs.y);
        atomicAdd(a + 2, ea.x);
        atomicAdd(a + 3, ea.y);
        atomicAdd(a + 4, 1.0f);
    }
    __syncthreads();

    float* p = partials + ((size_t)b * bps + blk) * (N_ * STATS);
    for (int i = threadIdx.x; i < N_ * STATS; i += blockDim.x) p[i] = acc[i];
}

// ---------------------------------------------------------------------------
// Kernel 2: reduce partials + dense finalize.
//   out[b][n][k] = (W[k]·[cnt*x, sum_xsrc, sum_ea] + cnt*bias[k]) / max(cnt,1)
// ---------------------------------------------------------------------------
__global__ __launch_bounds__(128) void finalize_kernel(
        const float* __restrict__ locs,
        const float* __restrict__ partials,
        const float* __restrict__ W,     // [EMBED][6]
        const float* __restrict__ bias,  // [EMBED]
        float*       __restrict__ out,   // [B][N][EMBED]
        int bps) {
    __shared__ float sWt[6 * EMBED];
    __shared__ float sb[EMBED];
    const int k = threadIdx.x;  // 0..127 = embedding channel
    #pragma unroll
    for (int j = 0; j < 6; ++j) sWt[j * EMBED + k] = W[k * 6 + j];
    sb[k] = bias[k];
    __syncthreads();

    const float w0 = sWt[0 * EMBED + k];
    const float w1 = sWt[1 * EMBED + k];
    const float w2 = sWt[2 * EMBED + k];
    const float w3 = sWt[3 * EMBED + k];
    const float w4 = sWt[4 * EMBED + k];
    const float w5 = sWt[5 * EMBED + k];
    const float bk = sb[k];

    for (int bn = blockIdx.x; bn < B_ * N_; bn += gridDim.x) {
        const int b = bn / N_;
        const int n = bn - b * N_;
        float s0 = 0.f, s1 = 0.f, s2 = 0.f, s3 = 0.f, cnt = 0.f;
        for (int blk = 0; blk < bps; ++blk) {
            const float* p = partials + (((size_t)b * bps + blk) * N_ + n) * STATS;
            s0 += p[0]; s1 += p[1]; s2 += p[2]; s3 += p[3]; cnt += p[4];
        }
        float2 x = *reinterpret_cast<const float2*>(locs + (size_t)bn * 2);
        float v = w0 * (cnt * x.x) + w1 * (cnt * x.y)
                + w2 * s0 + w3 * s1 + w4 * s2 + w5 * s3 + cnt * bk;
        out[(size_t)bn * EMBED + k] = v / fmaxf(cnt, 1.0f);
    }
}

extern "C" void kernel_launch(void* const* d_in, const int* in_sizes, int n_in,
                              void* d_out, int out_size, void* d_ws, size_t ws_size,
                              hipStream_t stream) {
    const float* locs       = (const float*)d_in[0];  // [B][N][2]
    const int*   edge_index = (const int*)  d_in[1];  // [B][2][E]
    const float* edge_attr  = (const float*)d_in[2];  // [B][E][2]
    const float* W          = (const float*)d_in[3];  // [128][6]
    const float* bias       = (const float*)d_in[4];  // [128]
    float* out = (float*)d_out;                       // [B][N][128]

    float* partials = (float*)d_ws;

    // Adaptive blocks-per-sample: largest power of 2 <= 16 whose partial
    // buffer fits in ws. (ws_size is fixed across calls -> deterministic.)
    int bps = 16;
    while (bps > 1 &&
           (size_t)B_ * bps * N_ * STATS * sizeof(float) > ws_size) {
        bps >>= 1;
    }
    const int epb = E_ / bps;  // 64000 divisible by 1,2,4,8,16

    // Edge scatter: B*bps blocks, LDS accumulate, coalesced partial flush.
    edge_scatter_lds<<<B_ * bps, 256, 0, stream>>>(
        locs, edge_index, edge_attr, partials, bps, epb);

    // Reduce + finalize: grid-stride over (b,n), 128 threads = 128 channels.
    finalize_kernel<<<2048, 128, 0, stream>>>(
        locs, partials, W, bias, out, bps);
}

// Round 3
// 82.562 us; speedup vs baseline: 6.7322x; 2.6291x over previous
//
#include <hip/hip_runtime.h>

// Problem constants (match reference setup_inputs)
#define B_    32
#define N_    2000
#define E_    64000
#define EMBED 128
#define STATS 5   // [sum_xsrc0, sum_xsrc1, sum_ea0, sum_ea1, cnt]
#define ROW_WORDS (N_ * STATS)      // 10000 floats = 40 KB per (b,blk) partial
#define ROW_VEC4  (ROW_WORDS / 4)   // 2500 float4

// ---------------------------------------------------------------------------
// Kernel 1: per-edge scatter into a per-block LDS accumulator (40 KB), then
// one coalesced float4 flush of the partial to global ws. No global atomics.
// Each thread processes 2 consecutive edges (int2 / float4 loads).
// ---------------------------------------------------------------------------
__global__ __launch_bounds__(256) void edge_scatter_lds(
        const float* __restrict__ locs,
        const int*   __restrict__ edge_index,
        const float* __restrict__ edge_attr,
        float*       __restrict__ partials,   // [B][bps][N][STATS]
        int bps_shift, int epb) {
    __shared__ float acc[ROW_WORDS];  // 40 KB

    const int b   = blockIdx.x >> bps_shift;
    const int blk = blockIdx.x & ((1 << bps_shift) - 1);

    for (int i = threadIdx.x; i < ROW_WORDS; i += blockDim.x) acc[i] = 0.0f;
    __syncthreads();

    const int*   eib = edge_index + (size_t)b * 2 * E_;
    const float* eab = edge_attr  + (size_t)b * E_ * 2;
    const float* xb  = locs       + (size_t)b * N_ * 2;

    const int e0 = blk * epb;
    const int e1 = e0 + epb;      // epb is even for bps in {1..32}
    for (int e = e0 + (int)threadIdx.x * 2; e < e1; e += blockDim.x * 2) {
        int2 src = *reinterpret_cast<const int2*>(eib + e);        // ei[b][0][e..e+1]
        int2 tgt = *reinterpret_cast<const int2*>(eib + E_ + e);   // ei[b][1][e..e+1]
        float2 xs0 = *reinterpret_cast<const float2*>(xb + (size_t)src.x * 2);
        float2 xs1 = *reinterpret_cast<const float2*>(xb + (size_t)src.y * 2);
        float4 ea  = *reinterpret_cast<const float4*>(eab + (size_t)e * 2);

        float* a0 = acc + tgt.x * STATS;
        atomicAdd(a0 + 0, xs0.x);
        atomicAdd(a0 + 1, xs0.y);
        atomicAdd(a0 + 2, ea.x);
        atomicAdd(a0 + 3, ea.y);
        atomicAdd(a0 + 4, 1.0f);
        float* a1 = acc + tgt.y * STATS;
        atomicAdd(a1 + 0, xs1.x);
        atomicAdd(a1 + 1, xs1.y);
        atomicAdd(a1 + 2, ea.z);
        atomicAdd(a1 + 3, ea.w);
        atomicAdd(a1 + 4, 1.0f);
    }
    __syncthreads();

    float4* p = reinterpret_cast<float4*>(partials) + (size_t)blockIdx.x * ROW_VEC4;
    const float4* av = reinterpret_cast<const float4*>(acc);
    for (int i = threadIdx.x; i < ROW_VEC4; i += blockDim.x) p[i] = av[i];
}

// ---------------------------------------------------------------------------
// Kernel 2: coalesced float4 reduction of partials over the bps axis.
//   accum[b][r] = sum_blk partials[b][blk][r]   (r in float4 units)
// ---------------------------------------------------------------------------
__global__ __launch_bounds__(256) void reduce_partials(
        const float4* __restrict__ partials,
        float4*       __restrict__ accum,    // [B][ROW_VEC4]
        int bps) {
    int i = blockIdx.x * blockDim.x + threadIdx.x;
    if (i >= B_ * ROW_VEC4) return;
    int b = i / ROW_VEC4;
    int r = i - b * ROW_VEC4;
    const float4* p = partials + (size_t)b * bps * ROW_VEC4 + r;
    float4 s = {0.f, 0.f, 0.f, 0.f};
    for (int k = 0; k < bps; ++k) {
        float4 v = p[(size_t)k * ROW_VEC4];
        s.x += v.x; s.y += v.y; s.z += v.z; s.w += v.w;
    }
    accum[i] = s;
}

// ---------------------------------------------------------------------------
// Kernel 3: dense finalize from compact accum (1.28 MB, L2-resident).
// 256 threads = 8 rows/iter; each thread computes 4 channels, float4 store.
//   out[bn][k] = (W[k]·[cnt*x, sum_xsrc, sum_ea] + cnt*bias[k]) / max(cnt,1)
// ---------------------------------------------------------------------------
__global__ __launch_bounds__(256) void finalize_kernel(
        const float* __restrict__ locs,
        const float* __restrict__ accum,  // [B*N][STATS]
        const float* __restrict__ W,      // [EMBED][6]
        const float* __restrict__ bias,   // [EMBED]
        float*       __restrict__ out) {  // [B][N][EMBED]
    const int lane32 = threadIdx.x & 31;
    const int rsub   = threadIdx.x >> 5;      // 0..7: row within group
    const int ch0    = lane32 * 4;            // first of 4 channels

    // Per-thread weights for 4 channels (24 + 4 regs), loaded once.
    float w[4][6], b4[4];
    #pragma unroll
    for (int c = 0; c < 4; ++c) {
        #pragma unroll
        for (int j = 0; j < 6; ++j) w[c][j] = W[(ch0 + c) * 6 + j];
        b4[c] = bias[ch0 + c];
    }

    float4* out4 = reinterpret_cast<float4*>(out);
    for (int bn0 = blockIdx.x * 8; bn0 < B_ * N_; bn0 += gridDim.x * 8) {
        const int bn = bn0 + rsub;
        const float* a = accum + (size_t)bn * STATS;
        float s0 = a[0], s1 = a[1], s2 = a[2], s3 = a[3], cnt = a[4];
        float2 x = *reinterpret_cast<const float2*>(locs + (size_t)bn * 2);
        float f0 = cnt * x.x, f1 = cnt * x.y;
        float inv = 1.0f / fmaxf(cnt, 1.0f);
        float4 v;
        v.x = (w[0][0]*f0 + w[0][1]*f1 + w[0][2]*s0 + w[0][3]*s1 + w[0][4]*s2 + w[0][5]*s3 + cnt*b4[0]) * inv;
        v.y = (w[1][0]*f0 + w[1][1]*f1 + w[1][2]*s0 + w[1][3]*s1 + w[1][4]*s2 + w[1][5]*s3 + cnt*b4[1]) * inv;
        v.z = (w[2][0]*f0 + w[2][1]*f1 + w[2][2]*s0 + w[2][3]*s1 + w[2][4]*s2 + w[2][5]*s3 + cnt*b4[2]) * inv;
        v.w = (w[3][0]*f0 + w[3][1]*f1 + w[3][2]*s0 + w[3][3]*s1 + w[3][4]*s2 + w[3][5]*s3 + cnt*b4[3]) * inv;
        out4[(size_t)bn * (EMBED / 4) + lane32] = v;
    }
}

extern "C" void kernel_launch(void* const* d_in, const int* in_sizes, int n_in,
                              void* d_out, int out_size, void* d_ws, size_t ws_size,
                              hipStream_t stream) {
    const float* locs       = (const float*)d_in[0];  // [B][N][2]
    const int*   edge_index = (const int*)  d_in[1];  // [B][2][E]
    const float* edge_attr  = (const float*)d_in[2];  // [B][E][2]
    const float* W          = (const float*)d_in[3];  // [128][6]
    const float* bias       = (const float*)d_in[4];  // [128]
    float* out = (float*)d_out;                       // [B][N][128]

    // Blocks-per-sample: largest power of 2 <= 32 such that
    // partials + accum fit in ws. (ws_size fixed -> deterministic.)
    int bps_shift = 5;
    const size_t accum_bytes = (size_t)B_ * ROW_WORDS * sizeof(float);
    while (bps_shift > 0 &&
           ((size_t)B_ << bps_shift) * ROW_WORDS * sizeof(float) + accum_bytes > ws_size) {
        --bps_shift;
    }
    const int bps = 1 << bps_shift;
    const int epb = E_ >> bps_shift;   // 64000/bps, even for bps<=32

    float* partials = (float*)d_ws;                                   // [B][bps][N][5]
    float* accum    = partials + (size_t)B_ * bps * ROW_WORDS;        // [B][N][5]

    // 1) Edge scatter: B*bps blocks, LDS accumulate, float4 flush.
    edge_scatter_lds<<<B_ * bps, 256, 0, stream>>>(
        locs, edge_index, edge_attr, partials, bps_shift, epb);

    // 2) Coalesced partial reduction.
    {
        const int total = B_ * ROW_VEC4;                // 80000
        reduce_partials<<<(total + 255) / 256, 256, 0, stream>>>(
            reinterpret_cast<const float4*>(partials),
            reinterpret_cast<float4*>(accum), bps);
    }

    // 3) Finalize: streaming 32.8 MB output write.
    finalize_kernel<<<2048, 256, 0, stream>>>(locs, accum, W, bias, out);
}